// Round 4
// baseline (584.023 us; speedup 1.0000x reference)
//
#include <hip/hip_runtime.h>

#define U 4096
#define S 8192
#define D 32
#define NUM_REGIONS 128
#define GA 0.1f

#define TUSERS 32      // users per block
#define TITEMS 256     // items per block
#define THREADS 256
#define GRID_X (U / TUSERS)   // 128
#define GRID_Y (S / TITEMS)   // 32
#define NBLOCKS (GRID_X * GRID_Y)

typedef short short8 __attribute__((ext_vector_type(8)));
typedef float f32x4 __attribute__((ext_vector_type(4)));

// fp32 -> bf16, round-to-nearest-even (inputs are tame gaussians; no NaN path)
__device__ __forceinline__ unsigned short f2bf(float f) {
    unsigned u = __float_as_uint(f);
    return (unsigned short)((u + 0x7FFFu + ((u >> 16) & 1u)) >> 16);
}

// ---------------- K1: bf16 conversion + region sums/counts (atomics) --------
// 128 blocks x 256 threads = 32768 threads.
//   user_emb: 131072 floats -> 4/thread (one float4), also atomicAdd into sums
//   item_emb: 262144 floats -> 8/thread (two float4)
//   counts:   threads g < U add 1 to counts[region[g]]
// sums/counts/loss_acc/done zeroed by the preceding memset node.

__global__ __launch_bounds__(256) void prep_kernel(
    const float* __restrict__ user_emb,
    const float* __restrict__ item_emb,
    const int* __restrict__ region_index,
    float* __restrict__ sums,          // [R, D]
    float* __restrict__ counts,        // [R]
    unsigned short* __restrict__ user_bf16,   // [U, D]
    unsigned short* __restrict__ item_bf16) { // [S, D]
    const int g = blockIdx.x * 256 + threadIdx.x;  // 0..32767

    // ---- user row chunk: 4 consecutive floats (d..d+3 of user u) ----
    {
        float4 v = ((const float4*)user_emb)[g];
        ushort4 o;
        o.x = f2bf(v.x); o.y = f2bf(v.y); o.z = f2bf(v.z); o.w = f2bf(v.w);
        ((ushort4*)user_bf16)[g] = o;
        int e0 = g * 4;
        int u = e0 >> 5, d = e0 & 31;
        int r = region_index[u];
        float* dst = &sums[r * D + d];
        atomicAdd(dst + 0, v.x);
        atomicAdd(dst + 1, v.y);
        atomicAdd(dst + 2, v.z);
        atomicAdd(dst + 3, v.w);
    }
    if (g < U) atomicAdd(&counts[region_index[g]], 1.0f);

    // ---- item chunk: 8 consecutive floats ----
    {
        float4 a = ((const float4*)item_emb)[2 * g];
        float4 b = ((const float4*)item_emb)[2 * g + 1];
        ushort4 oa, ob;
        oa.x = f2bf(a.x); oa.y = f2bf(a.y); oa.z = f2bf(a.z); oa.w = f2bf(a.w);
        ob.x = f2bf(b.x); ob.y = f2bf(b.y); ob.z = f2bf(b.z); ob.w = f2bf(b.w);
        ((ushort4*)item_bf16)[2 * g]     = oa;
        ((ushort4*)item_bf16)[2 * g + 1] = ob;
    }
}

// ---------------- K2: MFMA masked-MSE + fused LOO region loss + finalize ----
// Block tile: 32 users x 256 items. K=D=32 => ONE mfma_f32_16x16x32_bf16 per
// 16x16 output tile, no K-loop. 4 waves; wave w owns items [w*64, w*64+64):
// 2 user-subtiles x 4 item-subtiles = 8 MFMAs/wave.
// Verified layouts (m89/m91/m120): A[m=lane&15][k=(lane>>4)*8+j],
// B[n=lane&15][k=(lane>>4)*8+j], C/D: col(n)=lane&15, row(m)=(lane>>4)*4+reg.

__global__ __launch_bounds__(THREADS) void mse_kernel(
    const float* __restrict__ user_emb,
    const unsigned short* __restrict__ user_bf16,
    const unsigned short* __restrict__ item_bf16,
    const int* __restrict__ train_mask,
    const float* __restrict__ true_qos,
    const float* __restrict__ us_lossweight,
    const int* __restrict__ region_index,
    const float* __restrict__ sums,
    const float* __restrict__ counts,
    float* __restrict__ loss_acc,
    unsigned int* __restrict__ done_counter,
    float* __restrict__ out) {
    __shared__ unsigned short uL[TUSERS * D];   // 2 KB
    __shared__ unsigned short iL[TITEMS * D];   // 16 KB

    const int tid  = threadIdx.x;
    const int wave = tid >> 6;
    const int lane = tid & 63;
    const int ub = blockIdx.x * TUSERS;
    const int sb = blockIdx.y * TITEMS;

    // stage user tile (1024 ushorts): 256 threads x ushort4, coalesced
    ((ushort4*)uL)[tid] = ((const ushort4*)(user_bf16 + ub * D))[tid];
    // stage item tile (8192 ushorts = 1024 int4): 4 chunks/thread, coalesced
    {
        const int4* src = (const int4*)(item_bf16 + (size_t)sb * D);
        int4* dst = (int4*)iL;
        #pragma unroll
        for (int i = 0; i < 4; i++) dst[i * 256 + tid] = src[i * 256 + tid];
    }

    float lacc = 0.0f;

    // fused LOO region loss: only the y==0 slab, 32 users x 32 dims
    if (blockIdx.y == 0) {
        #pragma unroll
        for (int i = tid; i < TUSERS * D; i += THREADS) {
            int u = ub + (i >> 5), d = i & 31;
            int r = region_index[u];
            float c = counts[r];
            if (c > 1.0f) {
                float e = user_emb[u * D + d];
                float loo = (sums[r * D + d] - e) / fmaxf(c - 1.0f, 1.0f);
                lacc += GA * fabsf(e - loo);
            }
        }
    }

    __syncthreads();

    const int row16 = lane & 15;
    const int quad  = lane >> 4;
    const int koff  = quad * 8;

    // A fragments: 2 user subtiles
    short8 a0 = *(const short8*)&uL[(row16)      * D + koff];
    short8 a1 = *(const short8*)&uL[(16 + row16) * D + koff];
    // B fragments: 4 item subtiles of this wave
    const int ibase = wave * 64;
    short8 b0 = *(const short8*)&iL[(ibase +  0 + row16) * D + koff];
    short8 b1 = *(const short8*)&iL[(ibase + 16 + row16) * D + koff];
    short8 b2 = *(const short8*)&iL[(ibase + 32 + row16) * D + koff];
    short8 b3 = *(const short8*)&iL[(ibase + 48 + row16) * D + koff];

    f32x4 acc[2][4];
    #pragma unroll
    for (int i = 0; i < 2; i++)
        #pragma unroll
        for (int j = 0; j < 4; j++) acc[i][j] = (f32x4)0.0f;

    acc[0][0] = __builtin_amdgcn_mfma_f32_16x16x32_bf16(a0, b0, acc[0][0], 0, 0, 0);
    acc[0][1] = __builtin_amdgcn_mfma_f32_16x16x32_bf16(a0, b1, acc[0][1], 0, 0, 0);
    acc[0][2] = __builtin_amdgcn_mfma_f32_16x16x32_bf16(a0, b2, acc[0][2], 0, 0, 0);
    acc[0][3] = __builtin_amdgcn_mfma_f32_16x16x32_bf16(a0, b3, acc[0][3], 0, 0, 0);
    acc[1][0] = __builtin_amdgcn_mfma_f32_16x16x32_bf16(a1, b0, acc[1][0], 0, 0, 0);
    acc[1][1] = __builtin_amdgcn_mfma_f32_16x16x32_bf16(a1, b1, acc[1][1], 0, 0, 0);
    acc[1][2] = __builtin_amdgcn_mfma_f32_16x16x32_bf16(a1, b2, acc[1][2], 0, 0, 0);
    acc[1][3] = __builtin_amdgcn_mfma_f32_16x16x32_bf16(a1, b3, acc[1][3], 0, 0, 0);

    // epilogue: stream mask/qos/weight at the accumulator's (m,n) coordinates.
    // 16 lanes cover 16 consecutive n -> full 64B lines, dword-coalesced.
    #pragma unroll
    for (int ut = 0; ut < 2; ut++) {
        #pragma unroll
        for (int it = 0; it < 4; it++) {
            const int n = sb + ibase + it * 16 + row16;
            #pragma unroll
            for (int r = 0; r < 4; r++) {
                const int m = ub + ut * 16 + quad * 4 + r;
                const size_t ix = (size_t)m * S + n;
                float pre = acc[ut][it][r] * (float)train_mask[ix];
                float e = pre - true_qos[ix];
                lacc = fmaf(us_lossweight[ix] * e, e, lacc);
            }
        }
    }

    // wave64 reduce + one atomic per block; last block finalizes
    #pragma unroll
    for (int off = 32; off > 0; off >>= 1) lacc += __shfl_down(lacc, off, 64);
    __shared__ float wp[THREADS / 64];
    if ((lane) == 0) wp[wave] = lacc;
    __syncthreads();
    if (tid == 0) {
        float t = wp[0] + wp[1] + wp[2] + wp[3];
        atomicAdd(loss_acc, t);
        __threadfence();
        unsigned int nd = atomicAdd(done_counter, 1u);
        if (nd == NBLOCKS - 1) {
            out[0] = atomicAdd(loss_acc, 0.0f);  // device-coherent read
        }
    }
}

extern "C" void kernel_launch(void* const* d_in, const int* in_sizes, int n_in,
                              void* d_out, int out_size, void* d_ws, size_t ws_size,
                              hipStream_t stream) {
    const float* user_emb      = (const float*)d_in[0];
    const float* item_emb      = (const float*)d_in[1];
    const int*   train_mask    = (const int*)d_in[2];
    const float* true_qos      = (const float*)d_in[3];
    const float* us_lossweight = (const float*)d_in[4];
    const int*   region_index  = (const int*)d_in[5];
    float* out = (float*)d_out;

    float* ws       = (float*)d_ws;
    float* sums     = ws;                       // R*D = 4096 floats
    float* counts   = sums + NUM_REGIONS * D;   // 128
    float* loss_acc = counts + NUM_REGIONS;     // 1
    unsigned int* done_counter = (unsigned int*)(loss_acc + 1);
    // bf16 staging areas (16B-aligned at float offset 4240)
    unsigned short* user_bf16 = (unsigned short*)(ws + 4240);           // 256 KB
    unsigned short* item_bf16 = user_bf16 + (size_t)U * D;              // 512 KB

    // zero sums/counts/loss_acc/done (4226 floats)
    hipMemsetAsync(d_ws, 0, 4226 * sizeof(float), stream);

    prep_kernel<<<128, 256, 0, stream>>>(user_emb, item_emb, region_index,
                                         sums, counts, user_bf16, item_bf16);

    dim3 grid(GRID_X, GRID_Y);
    mse_kernel<<<grid, THREADS, 0, stream>>>(
        user_emb, user_bf16, item_bf16, train_mask, true_qos, us_lossweight,
        region_index, sums, counts, loss_acc, done_counter, out);
}